// Round 7
// baseline (309.425 us; speedup 1.0000x reference)
//
#include <hip/hip_runtime.h>
#include <hip/hip_bf16.h>
#include <stdint.h>

typedef __attribute__((ext_vector_type(8))) short short8;
typedef __attribute__((ext_vector_type(16))) float f32x16;

#define XPP_BYTES 66355200ull   // 8rh*8cw*2b*15rho*15cwo*18d*64ci*2B
#define XPP_SLACK 65536ull
#define WPP_BYTES 14155776ull   // 64hw*27tap*4ksl*2n*2hi*32c*8ci*2B

__device__ __forceinline__ void gl2lds16(const void* g, void* l) {
    __builtin_amdgcn_global_load_lds(
        (const __attribute__((address_space(1))) unsigned int*)g,
        (__attribute__((address_space(3))) unsigned int*)l, 16, 0, 0);
}

// ---------------- bzero: zero only X''' halo (rho=0 | cwo=0 | d in {0,17}) --
__global__ __launch_bounds__(256)
void bzero(uint4* __restrict__ xpp) {
    const uint4 z = {0u, 0u, 0u, 0u};
    const int total = 935936;
    for (int idx = blockIdx.x * 256 + threadIdx.x; idx < total;
         idx += gridDim.x * 256) {
        int u;
        if (idx < 276480) {
            int slab = idx / 2160, off = idx % 2160;
            u = slab * 32400 + off;
        } else if (idx < 534528) {
            int k = idx - 276480;
            int run = k / 144, off = k % 144;
            int slab = run / 14, rho = run % 14 + 1;
            u = slab * 32400 + rho * 2160 + off;
        } else {
            int k = idx - 534528;
            int run = k / 8, off = k % 8;
            int slab = run / 392, r2 = run % 392;
            int rho = r2 / 28 + 1, r3 = r2 % 28;
            int cwo = r3 / 2 + 1, d = (r3 & 1) * 17;
            u = slab * 32400 + rho * 2160 + cwo * 144 + d * 8 + off;
        }
        xpp[u] = z;
    }
}

// ---------------- T1: X (f32) -> X''' (bf16, space-to-depth, d-innermost) --
__global__ __launch_bounds__(512)
void xform_x(const float* __restrict__ xin, __hip_bfloat16* __restrict__ xpp) {
    extern __shared__ __hip_bfloat16 Xl[];
    const int bid = blockIdx.x;
    const int rho = bid % 14, d = (bid / 14) % 16, b = bid / 224;
    const int tid = threadIdx.x;
    for (int f = tid; f < 64 * 8 * 28; f += 512) {
        int ci = f / 224, rem = f % 224;
        int r = rem / 28, c4 = (rem % 28) * 4;
        const float4 v = *(const float4*)&xin[
            ((((size_t)b * 64 + ci) * 16 + d) * 112 + (rho * 8 + r)) * 112 + c4];
        const float vv[4] = {v.x, v.y, v.z, v.w};
#pragma unroll
        for (int u = 0; u < 4; ++u) {
            int c = c4 + u;
            Xl[(r * 112 + c) * 64 + (ci ^ ((c & 7) << 3))] = __float2bfloat16(vv[u]);
        }
    }
    __syncthreads();
    for (int f = tid; f < 896 * 8; f += 512) {
        int pos = f >> 3, j = f & 7;
        int r = pos / 112, c = pos % 112;
        int cw = c & 7, cwo = c >> 3;
        uint4 v = *(const uint4*)&Xl[pos * 64 + ((j * 8) ^ ((c & 7) << 3))];
        size_t dst = (((((size_t)(r * 8 + cw) * 2 + b) * 15 + (rho + 1)) * 15
                       + (cwo + 1)) * 18 + (d + 1)) * 64 + j * 8;
        *(uint4*)(xpp + dst) = v;
    }
}

// ---------------- T2: W (f32) -> W3[hw][tap][ksl4][n2][hi2][c32][ci8] ------
// B-fragment-ordered: per (tap,ksl,n) a wave reads one contiguous 1 KB.
__global__ __launch_bounds__(256)
void xform_w(const float* __restrict__ wt, uint4* __restrict__ wpp) {
    __shared__ __hip_bfloat16 lw[8 * 27 * 72];
    const int hw = blockIdx.x >> 3, cc = blockIdx.x & 7;
    for (int f = threadIdx.x; f < 8 * 64 * 27; f += 256) {
        int k = f % 27, ci = (f / 27) % 64, co = f / (27 * 64);
        float v = wt[(size_t)hw * 110592 + (size_t)(cc * 8 + co) * 1728 + ci * 27 + k];
        lw[(co * 27 + k) * 72 + ci] = __float2bfloat16(v);
    }
    __syncthreads();
    for (int f = threadIdx.x; f < 27 * 8 * 8; f += 256) {
        int cic = f % 8, co8 = (f / 8) % 8, k = f / 64;
        uint4 v = *(const uint4*)&lw[(co8 * 27 + k) * 72 + cic * 8];
        const int co = cc * 8 + co8;
        size_t dst = ((size_t)hw * 27 + k) * 512 + (cic >> 1) * 128
                   + (co >> 5) * 64 + (cic & 1) * 32 + (co & 31);
        wpp[dst] = v;
    }
}

// ---------------- GEMM: per (h,w,b,mcp): [448m x 64co], m=(rho2,wo14,t16) --
// 7 waves x (2 m-tiles-32 x 2 n-tiles-32), mfma_f32_32x32x16_bf16.
// 18 windows (9 (kh,kw) x 2 ci-half); A in 3x35KB LDS ring (2-ahead, counted
// vmcnt W0:5 steady:17 W17:12); B global->reg, 1 window ahead (L2-resident).

#define WAITVM_(N) asm volatile("s_waitcnt vmcnt(" #N ")" ::: "memory")
#define WAITVM(N) WAITVM_(N)

#define STG(S) do { if ((S) < 18) {                                          \
    const int rr_ = (S) >> 1, hf_ = (S) & 1;                                 \
    const int r0_ = h + (rr_ / 3) - 7, c0_ = w + (rr_ % 3) - 7;              \
    const char* ap_ = (const char*)xpp +                                     \
        (size_t)(((((r0_ & 7) * 8 + (c0_ & 7)) * 2 + b) * 15                 \
                  + ((r0_ >> 3) + 1 + 2 * mcp)) * 15 + ((c0_ >> 3) + 1))     \
        * 2304 + hf_ * 64;                                                   \
    char* Ad_ = smem + ((S) % 3) * 35840;                                    \
    _Pragma("unroll")                                                        \
    for (int i_ = 0; i_ < 5; ++i_)                                           \
        gl2lds16(ap_ + srcoff[i_], Ad_ + (uint32_t)(tid + i_ * 448) * 16);   \
} } while (0)

#define LDB(S, DST) do { if ((S) < 18) {                                     \
    const int rr_ = (S) >> 1, hf_ = (S) & 1;                                 \
    _Pragma("unroll")                                                        \
    for (int kd_ = 0; kd_ < 3; ++kd_)                                        \
    _Pragma("unroll")                                                        \
    for (int ks_ = 0; ks_ < 2; ++ks_)                                        \
    _Pragma("unroll")                                                        \
    for (int n_ = 0; n_ < 2; ++n_)                                           \
        DST[kd_ * 4 + ks_ * 2 + n_] = *(const short8*)(wbase                 \
            + (size_t)((kd_ * 9 + rr_) * 4 + hf_ * 2 + ks_) * 2048          \
            + n_ * 1024 + (uint32_t)lane * 16);                              \
} } while (0)

#define WIN(S, CUR, NXT, WN) do {                                            \
    WAITVM(WN);                                                              \
    __builtin_amdgcn_s_barrier();                                            \
    LDB((S) + 1, NXT);                                                       \
    __builtin_amdgcn_sched_barrier(0);                                       \
    STG((S) + 2);                                                            \
    __builtin_amdgcn_sched_barrier(0);                                       \
    {   const char* Ab_ = smem + ((S) % 3) * 35840;                          \
        _Pragma("unroll")                                                    \
        for (int kd = 0; kd < 3; ++kd)                                       \
        _Pragma("unroll")                                                    \
        for (int ks = 0; ks < 2; ++ks) {                                     \
            short8 a0_ = *(const short8*)(Ab_ + woB + rofs[kd][ks]);         \
            short8 a1_ = *(const short8*)(Ab_ + 16128 + woB + rofs[kd][ks]); \
            __builtin_amdgcn_s_setprio(1);                                   \
            acc00 = __builtin_amdgcn_mfma_f32_32x32x16_bf16(                 \
                a0_, CUR[kd * 4 + ks * 2 + 0], acc00, 0, 0, 0);              \
            acc01 = __builtin_amdgcn_mfma_f32_32x32x16_bf16(                 \
                a0_, CUR[kd * 4 + ks * 2 + 1], acc01, 0, 0, 0);              \
            acc10 = __builtin_amdgcn_mfma_f32_32x32x16_bf16(                 \
                a1_, CUR[kd * 4 + ks * 2 + 0], acc10, 0, 0, 0);              \
            acc11 = __builtin_amdgcn_mfma_f32_32x32x16_bf16(                 \
                a1_, CUR[kd * 4 + ks * 2 + 1], acc11, 0, 0, 0);              \
            __builtin_amdgcn_s_setprio(0);                                   \
        } }                                                                  \
} while (0)

__global__ __launch_bounds__(448, 1)
void patgemm(const __hip_bfloat16* __restrict__ xpp,
             const char* __restrict__ wpp,
             const float* __restrict__ bs,
             float* __restrict__ out) {
    extern __shared__ char smem[];  // 3 x 35840 B A half-line ring
    const int bid = blockIdx.x;
    const int h = bid & 7, k = bid >> 3;
    const int w = k & 7, b = (k >> 3) & 1, mcp = k >> 4;   // mcp 0..6
    const int hw = h * 8 + w;
    const int tid = threadIdx.x, wv = tid >> 6, lane = tid & 63;
    const int c31 = lane & 31, hi = lane >> 5;

    // A staging source offsets: slot u = ((rs*14+wo)*18+d)*4+g' ; g = g'^swz(d)
    uint32_t srcoff[5];
#pragma unroll
    for (int i = 0; i < 5; ++i) {
        int u = tid + i * 448; if (u > 2015) u = 2015;
        int rs = u / 1008, rem = u - rs * 1008;
        int wo = rem / 72, r2 = rem - wo * 72;
        int d = r2 >> 2, gp = r2 & 3, g = gp ^ ((d >> 1) & 3);
        srcoff[i] = (uint32_t)(rs * 34560 + wo * 2304 + d * 128 + g * 16);
    }
    // A fragment read offsets: row r=lane&31 -> wo_sub=r>>4, t=r&15, d=t+kd
    const uint32_t woB = (uint32_t)((2 * wv + ((lane >> 4) & 1)) * 1152);
    uint32_t rofs[3][2];
#pragma unroll
    for (int kd = 0; kd < 3; ++kd)
#pragma unroll
        for (int ks = 0; ks < 2; ++ks) {
            int d = (lane & 15) + kd;
            rofs[kd][ks] = (uint32_t)(d * 64
                + (((ks * 2 + hi) ^ ((d >> 1) & 3)) << 4));
        }

    f32x16 acc00 = {0}, acc01 = {0}, acc10 = {0}, acc11 = {0};

    const char* wbase = wpp + (size_t)hw * 27 * 8192;
    short8 bfr0[12], bfr1[12];

    // prologue — per-wave VMEM FIFO: [LDB(0)x12, STG(0)x5, STG(1)x5]
    LDB(0, bfr0);
    __builtin_amdgcn_sched_barrier(0);
    STG(0);
    STG(1);

    WIN(0,  bfr0, bfr1, 5);
    WIN(1,  bfr1, bfr0, 17);
    WIN(2,  bfr0, bfr1, 17);
    WIN(3,  bfr1, bfr0, 17);
    WIN(4,  bfr0, bfr1, 17);
    WIN(5,  bfr1, bfr0, 17);
    WIN(6,  bfr0, bfr1, 17);
    WIN(7,  bfr1, bfr0, 17);
    WIN(8,  bfr0, bfr1, 17);
    WIN(9,  bfr1, bfr0, 17);
    WIN(10, bfr0, bfr1, 17);
    WIN(11, bfr1, bfr0, 17);
    WIN(12, bfr0, bfr1, 17);
    WIN(13, bfr1, bfr0, 17);
    WIN(14, bfr0, bfr1, 17);
    WIN(15, bfr1, bfr0, 17);
    WIN(16, bfr0, bfr1, 17);
    WIN(17, bfr1, bfr0, 12);

    // epilogue: D col=lane&31 (co within n-tile), row=(r&3)+8*(r>>2)+4*hi
    const float* bsl = bs + hw * 64;
#pragma unroll
    for (int mi = 0; mi < 2; ++mi) {
        const int y = 8 * (2 * mcp + mi) + h;
#pragma unroll
        for (int n = 0; n < 2; ++n) {
            const f32x16 A = (mi == 0) ? (n == 0 ? acc00 : acc01)
                                       : (n == 0 ? acc10 : acc11);
            const int co = n * 32 + c31;
            const float bv = bsl[co];
#pragma unroll
            for (int r = 0; r < 16; ++r) {
                const int row = (r & 3) + 8 * (r >> 2) + 4 * hi;
                const int wo = 2 * wv + (row >> 4);
                const int t = row & 15;
                out[(((size_t)(b * 64 + co) * 16 + t) * 112 + y) * 112
                    + 8 * wo + w] = A[r] + bv;
            }
        }
    }
}

// ---------------- fallback: round-1 fp32 kernel (used if ws too small) -----
#define XL_ROWSTRIDE 116
#define WL_WSTRIDE (17*27)

__global__ __launch_bounds__(256, 3)
void patconv3d_fp32(const float* __restrict__ xin,
                    const float* __restrict__ wt,
                    const float* __restrict__ bs,
                    float* __restrict__ out) {
    __shared__ float Xl[3*3*7*XL_ROWSTRIDE];
    __shared__ float Wl[8*WL_WSTRIDE];
    const int bid = blockIdx.x;
    const int ct = bid & 3, hb = (bid >> 2) & 1, h = (bid >> 3) & 7;
    const int t = (bid >> 6) & 15, b = (bid >> 10) & 1;
    const int tid = threadIdx.x;
    const int xl = tid & 127, cg = tid >> 7;
    const int xr = (xl < 112) ? xl : 111;
    const int wq = xl & 7;
    float acc[8][7];
#pragma unroll
    for (int c = 0; c < 8; ++c)
#pragma unroll
        for (int ho = 0; ho < 7; ++ho) acc[c][ho] = 0.f;
    for (int ci = 0; ci < 64; ++ci) {
        __syncthreads();
        for (int idx = tid; idx < 3 * 3 * 7 * 114; idx += 256) {
            int c = idx % 114, rest = idx / 114;
            int ho = rest % 7; rest /= 7;
            int kh = rest % 3, kd = rest / 3;
            int r = 8 * (hb * 7 + ho) + h + kh - 7;
            int d = t + kd - 1, colx = c - 7;
            float v = 0.f;
            if (r >= 0 && d >= 0 && d < 16 && colx >= 0)
                v = xin[(((size_t)(b * 64 + ci) * 16 + d) * 112 + r) * 112 + colx];
            Xl[((kd * 3 + kh) * 7 + ho) * XL_ROWSTRIDE + c] = v;
        }
        for (int idx = tid; idx < 8 * 16 * 27; idx += 256) {
            int k2 = idx % 27, rest = idx / 27;
            int co_l = rest % 16, wi = rest / 16;
            Wl[wi * WL_WSTRIDE + co_l * 27 + k2] =
                wt[(((size_t)(h * 8 + wi) * 64 + (ct * 16 + co_l)) * 64 + ci) * 27 + k2];
        }
        __syncthreads();
#pragma unroll
        for (int kd = 0; kd < 3; ++kd)
#pragma unroll
            for (int kh = 0; kh < 3; ++kh)
#pragma unroll
                for (int kw = 0; kw < 3; ++kw) {
                    const int k2 = (kd * 3 + kh) * 3 + kw;
                    float xv[7];
#pragma unroll
                    for (int ho = 0; ho < 7; ++ho)
                        xv[ho] = Xl[((kd * 3 + kh) * 7 + ho) * XL_ROWSTRIDE + xr + kw];
                    float wv[8];
#pragma unroll
                    for (int c = 0; c < 8; ++c)
                        wv[c] = Wl[wq * WL_WSTRIDE + (cg * 8 + c) * 27 + k2];
#pragma unroll
                    for (int c = 0; c < 8; ++c)
#pragma unroll
                        for (int ho = 0; ho < 7; ++ho)
                            acc[c][ho] += wv[c] * xv[ho];
                }
    }
    if (xl < 112) {
#pragma unroll
        for (int c = 0; c < 8; ++c) {
            const int co = ct * 16 + cg * 8 + c;
            const float bv = bs[(h * 8 + wq) * 64 + co];
#pragma unroll
            for (int ho = 0; ho < 7; ++ho) {
                const int y = 8 * (hb * 7 + ho) + h;
                out[(((size_t)(b * 64 + co) * 16 + t) * 112 + y) * 112 + xl] = acc[c][ho] + bv;
            }
        }
    }
}

extern "C" void kernel_launch(void* const* d_in, const int* in_sizes, int n_in,
                              void* d_out, int out_size, void* d_ws, size_t ws_size,
                              hipStream_t stream) {
    const float* x  = (const float*)d_in[0];
    const float* wg = (const float*)d_in[1];
    const float* bi = (const float*)d_in[2];
    float* out = (float*)d_out;
    if (ws_size >= XPP_BYTES + XPP_SLACK + WPP_BYTES) {
        __hip_bfloat16* xpp = (__hip_bfloat16*)d_ws;
        char* wpp = (char*)d_ws + XPP_BYTES + XPP_SLACK;
        bzero<<<1024, 256, 0, stream>>>((uint4*)d_ws);
        xform_x<<<448, 512, 114688, stream>>>(x, xpp);
        xform_w<<<512, 256, 0, stream>>>(wg, (uint4*)wpp);
        patgemm<<<896, 448, 107520, stream>>>(xpp, wpp, bi, out);
    } else {
        patconv3d_fp32<<<2048, 256, 0, stream>>>(x, wg, bi, out);
    }
}

// Round 8
// 298.233 us; speedup vs baseline: 1.0375x; 1.0375x over previous
//
#include <hip/hip_runtime.h>
#include <hip/hip_bf16.h>
#include <stdint.h>

typedef __attribute__((ext_vector_type(8))) short short8;
typedef __attribute__((ext_vector_type(4))) float f32x4;

#define WPP_BYTES 14155776ull   // 64hw*27tap*64co*64ci*2B  (placed FIRST in ws)
#define XPP_BYTES 66355200ull   // 8rh*8cw*2b*15rho*15cwo*18d*64ci*2B

__device__ __forceinline__ void gl2lds16(const void* g, void* l) {
    __builtin_amdgcn_global_load_lds(
        (const __attribute__((address_space(1))) unsigned int*)g,
        (__attribute__((address_space(3))) unsigned int*)l, 16, 0, 0);
}

// ---------------- bzero: zero only X''' halo (rho=0 | cwo=0 | d in {0,17}) --
__global__ __launch_bounds__(256)
void bzero(uint4* __restrict__ xpp) {
    const uint4 z = {0u, 0u, 0u, 0u};
    const int total = 935936;
    for (int idx = blockIdx.x * 256 + threadIdx.x; idx < total;
         idx += gridDim.x * 256) {
        int u;
        if (idx < 276480) {
            int slab = idx / 2160, off = idx % 2160;
            u = slab * 32400 + off;
        } else if (idx < 534528) {
            int k = idx - 276480;
            int run = k / 144, off = k % 144;
            int slab = run / 14, rho = run % 14 + 1;
            u = slab * 32400 + rho * 2160 + off;
        } else {
            int k = idx - 534528;
            int run = k / 8, off = k % 8;
            int slab = run / 392, r2 = run % 392;
            int rho = r2 / 28 + 1, r3 = r2 % 28;
            int cwo = r3 / 2 + 1, d = (r3 & 1) * 17;
            u = slab * 32400 + rho * 2160 + cwo * 144 + d * 8 + off;
        }
        xpp[u] = z;
    }
}

// ---------------- T1: X (f32) -> X''' (bf16, space-to-depth, d-innermost) --
__global__ __launch_bounds__(512)
void xform_x(const float* __restrict__ xin, __hip_bfloat16* __restrict__ xpp) {
    extern __shared__ __hip_bfloat16 Xl[];
    const int bid = blockIdx.x;
    const int rho = bid % 14, d = (bid / 14) % 16, b = bid / 224;
    const int tid = threadIdx.x;
    for (int f = tid; f < 64 * 8 * 28; f += 512) {
        int ci = f / 224, rem = f % 224;
        int r = rem / 28, c4 = (rem % 28) * 4;
        const float4 v = *(const float4*)&xin[
            ((((size_t)b * 64 + ci) * 16 + d) * 112 + (rho * 8 + r)) * 112 + c4];
        const float vv[4] = {v.x, v.y, v.z, v.w};
#pragma unroll
        for (int u = 0; u < 4; ++u) {
            int c = c4 + u;
            Xl[(r * 112 + c) * 64 + (ci ^ ((c & 7) << 3))] = __float2bfloat16(vv[u]);
        }
    }
    __syncthreads();
    for (int f = tid; f < 896 * 8; f += 512) {
        int pos = f >> 3, j = f & 7;
        int r = pos / 112, c = pos % 112;
        int cw = c & 7, cwo = c >> 3;
        uint4 v = *(const uint4*)&Xl[pos * 64 + ((j * 8) ^ ((c & 7) << 3))];
        size_t dst = (((((size_t)(r * 8 + cw) * 2 + b) * 15 + (rho + 1)) * 15
                       + (cwo + 1)) * 18 + (d + 1)) * 64 + j * 8;
        *(uint4*)(xpp + dst) = v;
    }
}

// ---------------- T2: W (f32) -> W''[hw][tap][co64][cic8x16B] (bf16) -------
__global__ __launch_bounds__(256)
void xform_w(const float* __restrict__ wt, __hip_bfloat16* __restrict__ wpp) {
    __shared__ __hip_bfloat16 lw[8 * 27 * 72];
    const int hw = blockIdx.x >> 3, cc = blockIdx.x & 7;
    for (int f = threadIdx.x; f < 8 * 64 * 27; f += 256) {
        int k = f % 27, ci = (f / 27) % 64, co = f / (27 * 64);
        float v = wt[(size_t)hw * 110592 + (size_t)(cc * 8 + co) * 1728 + ci * 27 + k];
        lw[(co * 27 + k) * 72 + ci] = __float2bfloat16(v);
    }
    __syncthreads();
    for (int f = threadIdx.x; f < 27 * 8 * 8; f += 256) {
        int cic = f % 8, co = (f / 8) % 8, k = f / 64;
        uint4 v = *(const uint4*)&lw[(co * 27 + k) * 72 + cic * 8];
        size_t dst = (((size_t)hw * 27 + k) * 64 + (cc * 8 + co)) * 64 + cic * 8;
        *(uint4*)(wpp + dst) = v;
    }
}

// ---------------- GEMM: per (h,w,b,mc): [224m x 64co], m=(wo14,t16) --------
// 448 thr / 7 waves; wave = 2 m-tiles x full N. 54 windows (27 taps x 2 ci-
// halves). A ring3 x 14336, B ring3 x 8192 + 1KB dump = 68.6 KB (2 blk/CU).
// ALL K-loop VMEM = global_load_lds (uniform/thread) -> exact counted vmcnt:
// even windows wait 2 (need B(t),A(S)), odd wait 4 (need A(S)); loads span
// 2-3 windows. Issue/window: even [B(t+1):2, A(S+2):2], odd [A(S+2):2].

#define WAITVM_(N) asm volatile("s_waitcnt vmcnt(" #N ")" ::: "memory")
#define WAITVM(N) WAITVM_(N)

#define STGA(T, RN, HFA) do {                                                \
    const int t_ = (T), kd_ = t_ / 9, r9_ = t_ % 9;                          \
    const int r0_ = h + (r9_ / 3) - 7, c0_ = w + (r9_ % 3) - 7;              \
    const char* ap_ = xppc +                                                 \
        (size_t)(((((r0_ & 7) * 8 + (c0_ & 7)) * 2 + b) * 15                 \
                  + ((r0_ >> 3) + 1 + mc)) * 15 + ((c0_ >> 3) + 1)) * 2304   \
        + kd_ * 128 + (HFA) * 64;                                            \
    char* Ad_ = smem + (RN) * 14336;                                         \
    gl2lds16(ap_ + aoff[0], Ad_ + tid * 16);                                 \
    gl2lds16(ap_ + aoff[1], Ad_ + 7168 + tid * 16);                          \
} while (0)

#define STGB(T, RN) do {                                                     \
    const char* bp_ = wppc + (size_t)hw * 221184 + (size_t)(T) * 8192;       \
    char* Bd_ = smem + 43008 + (RN) * 8192;                                  \
    gl2lds16(bp_ + boff[0], Bd_ + tid * 16);                                 \
    char* d1_ = (wv == 0) ? (Bd_ + 7168 + (tid & 63) * 16)                   \
                          : (smem + 67584 + (tid & 63) * 16);                \
    gl2lds16(bp_ + boff[1], d1_);                                            \
} while (0)

#define MF(mi, n, AF, BF) acc[mi][n] =                                       \
    __builtin_amdgcn_mfma_f32_16x16x32_bf16(AF, BF, acc[mi][n], 0, 0, 0)

#define WIN(RA, HF, RB, DOB, TB, RBN, DOA, TA, RAN, HFA, WN) do {            \
    WAITVM(WN);                                                              \
    __builtin_amdgcn_s_barrier();                                            \
    const char* Ab_ = smem + (RA) * 14336;                                   \
    const char* Bb_ = smem + 43008 + (RB) * 8192;                            \
    short8 af0 = *(const short8*)(Ab_ + wv * 2048 + arow);                   \
    short8 af1 = *(const short8*)(Ab_ + wv * 2048 + 1024 + arow);            \
    short8 bf0 = *(const short8*)(Bb_ + bofsw[HF]);                          \
    short8 bf1 = *(const short8*)(Bb_ + 2048 + bofsw[HF]);                   \
    short8 bf2 = *(const short8*)(Bb_ + 4096 + bofsw[HF]);                   \
    short8 bf3 = *(const short8*)(Bb_ + 6144 + bofsw[HF]);                   \
    __builtin_amdgcn_sched_barrier(0);                                       \
    if (DOB) STGB(TB, RBN);                                                  \
    if (DOA) STGA(TA, RAN, HFA);                                             \
    __builtin_amdgcn_sched_barrier(0);                                       \
    __builtin_amdgcn_s_setprio(1);                                           \
    MF(0, 0, af0, bf0); MF(0, 1, af0, bf1);                                  \
    MF(0, 2, af0, bf2); MF(0, 3, af0, bf3);                                  \
    MF(1, 0, af1, bf0); MF(1, 1, af1, bf1);                                  \
    MF(1, 2, af1, bf2); MF(1, 3, af1, bf3);                                  \
    __builtin_amdgcn_s_setprio(0);                                           \
} while (0)

__global__ __launch_bounds__(448, 3)
void patgemm(const __hip_bfloat16* __restrict__ xpp,
             const char* __restrict__ wppc,
             const float* __restrict__ bs,
             float* __restrict__ out) {
    extern __shared__ char smem[];  // A 3x14336 | B 3x8192 | dump 1024
    const char* xppc = (const char*)xpp;
    const int bid = blockIdx.x;
    const int h = bid & 7, k = bid >> 3;
    const int w = k & 7, b = (k >> 3) & 1, mc = k >> 4;   // mc 0..13
    const int hw = h * 8 + w;
    const int tid = threadIdx.x, wv = tid >> 6;
    const int lane = tid & 63, col = lane & 15, quad = lane >> 4;

    // A stage src offsets: u -> row m=u>>2 (wo=m>>4, rt=m&15), chunk c'=u&3,
    // src chunk q = c' ^ ((m>>2)&3)  (read-side swizzle key = (col>>2)&3)
    uint32_t aoff[2];
#pragma unroll
    for (int i = 0; i < 2; ++i) {
        int u = tid + i * 448;
        aoff[i] = (uint32_t)((u >> 6) * 2304 + ((u >> 2) & 15) * 128
                             + (((u & 3) ^ ((u >> 4) & 3)) << 4));
    }
    // B stage src offsets: u -> co=u>>3, ch=u&7, src chunk = ch^(co&7)
    uint32_t boff[2];
#pragma unroll
    for (int i = 0; i < 2; ++i) {
        int u = tid + i * 448;
        boff[i] = (uint32_t)((u >> 3) * 128 + (((u & 7) ^ ((u >> 3) & 7)) << 4));
    }
    // read offsets
    const uint32_t arow = (uint32_t)(col * 64 + ((quad ^ ((col >> 2) & 3)) << 4));
    uint32_t bofsw[2];
#pragma unroll
    for (int hf = 0; hf < 2; ++hf)
        bofsw[hf] = (uint32_t)(col * 128 + (((hf * 4 + quad) ^ (col & 7)) << 4));

    f32x4 acc[2][4];
#pragma unroll
    for (int mi = 0; mi < 2; ++mi)
#pragma unroll
        for (int n = 0; n < 4; ++n) acc[mi][n] = (f32x4){0.f, 0.f, 0.f, 0.f};

    // prologue: FIFO per thread = [B(0):2, A(0):2, A(1):2]
    STGB(0, 0);
    __builtin_amdgcn_sched_barrier(0);
    STGA(0, 0, 0);
    STGA(0, 1, 1);

#pragma unroll 1
    for (int g = 0; g < 8; ++g) {   // windows 6g..6g+5, taps 3g..3g+2
        const int t1 = 3 * g + 1, t2 = 3 * g + 2, t3 = 3 * g + 3;
        WIN(0, 0, 0,  1, t1, 1,  1, t1, 2, 0,  2);
        WIN(1, 1, 0,  0, 0, 0,   1, t1, 0, 1,  4);
        WIN(2, 0, 1,  1, t2, 2,  1, t2, 1, 0,  2);
        WIN(0, 1, 1,  0, 0, 0,   1, t2, 2, 1,  4);
        WIN(1, 0, 2,  1, t3, 0,  1, t3, 0, 0,  2);
        WIN(2, 1, 2,  0, 0, 0,   1, t3, 1, 1,  4);
    }
    // epilogue group g=8: taps 24,25,26
    WIN(0, 0, 0,  1, 25, 1,  1, 25, 2, 0,  2);
    WIN(1, 1, 0,  0, 0, 0,   1, 25, 0, 1,  4);
    WIN(2, 0, 1,  1, 26, 2,  1, 26, 1, 0,  2);
    WIN(0, 1, 1,  0, 0, 0,   1, 26, 2, 1,  4);
    WIN(1, 0, 2,  0, 0, 0,   0, 0, 0, 0,   2);
    WIN(2, 1, 2,  0, 0, 0,   0, 0, 0, 0,   0);

    // epilogue: D col=lane&15 (co within n-tile), row=quad*4+jj = t; wo=2wv+mi
    const float* bsl = bs + hw * 64;
    const int y = 8 * mc + h;
#pragma unroll
    for (int mi = 0; mi < 2; ++mi) {
        const int x = 8 * (2 * wv + mi) + w;
#pragma unroll
        for (int n = 0; n < 4; ++n) {
            const int co = n * 16 + col;
            const float bv = bsl[co];
#pragma unroll
            for (int jj = 0; jj < 4; ++jj) {
                const int t = quad * 4 + jj;
                out[((((size_t)b * 64 + co) * 16 + t) * 112 + y) * 112 + x]
                    = acc[mi][n][jj] + bv;
            }
        }
    }
}

// ---------------- fallback: round-1 fp32 kernel (used if ws too small) -----
#define XL_ROWSTRIDE 116
#define WL_WSTRIDE (17*27)

__global__ __launch_bounds__(256, 3)
void patconv3d_fp32(const float* __restrict__ xin,
                    const float* __restrict__ wt,
                    const float* __restrict__ bs,
                    float* __restrict__ out) {
    __shared__ float Xl[3*3*7*XL_ROWSTRIDE];
    __shared__ float Wl[8*WL_WSTRIDE];
    const int bid = blockIdx.x;
    const int ct = bid & 3, hb = (bid >> 2) & 1, h = (bid >> 3) & 7;
    const int t = (bid >> 6) & 15, b = (bid >> 10) & 1;
    const int tid = threadIdx.x;
    const int xl = tid & 127, cg = tid >> 7;
    const int xr = (xl < 112) ? xl : 111;
    const int wq = xl & 7;
    float acc[8][7];
#pragma unroll
    for (int c = 0; c < 8; ++c)
#pragma unroll
        for (int ho = 0; ho < 7; ++ho) acc[c][ho] = 0.f;
    for (int ci = 0; ci < 64; ++ci) {
        __syncthreads();
        for (int idx = tid; idx < 3 * 3 * 7 * 114; idx += 256) {
            int c = idx % 114, rest = idx / 114;
            int ho = rest % 7; rest /= 7;
            int kh = rest % 3, kd = rest / 3;
            int r = 8 * (hb * 7 + ho) + h + kh - 7;
            int d = t + kd - 1, colx = c - 7;
            float v = 0.f;
            if (r >= 0 && d >= 0 && d < 16 && colx >= 0)
                v = xin[(((size_t)(b * 64 + ci) * 16 + d) * 112 + r) * 112 + colx];
            Xl[((kd * 3 + kh) * 7 + ho) * XL_ROWSTRIDE + c] = v;
        }
        for (int idx = tid; idx < 8 * 16 * 27; idx += 256) {
            int k2 = idx % 27, rest = idx / 27;
            int co_l = rest % 16, wi = rest / 16;
            Wl[wi * WL_WSTRIDE + co_l * 27 + k2] =
                wt[(((size_t)(h * 8 + wi) * 64 + (ct * 16 + co_l)) * 64 + ci) * 27 + k2];
        }
        __syncthreads();
#pragma unroll
        for (int kd = 0; kd < 3; ++kd)
#pragma unroll
            for (int kh = 0; kh < 3; ++kh)
#pragma unroll
                for (int kw = 0; kw < 3; ++kw) {
                    const int k2 = (kd * 3 + kh) * 3 + kw;
                    float xv[7];
#pragma unroll
                    for (int ho = 0; ho < 7; ++ho)
                        xv[ho] = Xl[((kd * 3 + kh) * 7 + ho) * XL_ROWSTRIDE + xr + kw];
                    float wv[8];
#pragma unroll
                    for (int c = 0; c < 8; ++c)
                        wv[c] = Wl[wq * WL_WSTRIDE + (cg * 8 + c) * 27 + k2];
#pragma unroll
                    for (int c = 0; c < 8; ++c)
#pragma unroll
                        for (int ho = 0; ho < 7; ++ho)
                            acc[c][ho] += wv[c] * xv[ho];
                }
    }
    if (xl < 112) {
#pragma unroll
        for (int c = 0; c < 8; ++c) {
            const int co = ct * 16 + cg * 8 + c;
            const float bv = bs[(h * 8 + wq) * 64 + co];
#pragma unroll
            for (int ho = 0; ho < 7; ++ho) {
                const int y = 8 * (hb * 7 + ho) + h;
                out[(((size_t)(b * 64 + co) * 16 + t) * 112 + y) * 112 + xl] = acc[c][ho] + bv;
            }
        }
    }
}

extern "C" void kernel_launch(void* const* d_in, const int* in_sizes, int n_in,
                              void* d_out, int out_size, void* d_ws, size_t ws_size,
                              hipStream_t stream) {
    const float* x  = (const float*)d_in[0];
    const float* wg = (const float*)d_in[1];
    const float* bi = (const float*)d_in[2];
    float* out = (float*)d_out;
    if (ws_size >= WPP_BYTES + XPP_BYTES) {
        __hip_bfloat16* wpp = (__hip_bfloat16*)d_ws;           // W'' first:
        __hip_bfloat16* xpp = (__hip_bfloat16*)((char*)d_ws + WPP_BYTES);
        // B staging over-run (dump lanes) reads past W'' into X''' — in-bounds.
        bzero<<<1024, 256, 0, stream>>>((uint4*)xpp);
        xform_x<<<448, 512, 114688, stream>>>(x, xpp);
        xform_w<<<512, 256, 0, stream>>>(wg, wpp);
        patgemm<<<1792, 448, 68608, stream>>>(xpp, (const char*)wpp, bi, out);
    } else {
        patconv3d_fp32<<<2048, 256, 0, stream>>>(x, wg, bi, out);
    }
}

// Round 10
// 254.967 us; speedup vs baseline: 1.2136x; 1.1697x over previous
//
#include <hip/hip_runtime.h>
#include <hip/hip_bf16.h>
#include <stdint.h>

typedef __attribute__((ext_vector_type(8))) short short8;
typedef __attribute__((ext_vector_type(4))) float f32x4;

#define WPP_BYTES 14155776ull   // 64hw*27tap*64co*64ci*2B (first in ws)
#define XPP_BYTES 66355200ull   // 8rh*8cw*2b*15rho*15cwo*18d*64ci*2B

__device__ __forceinline__ void gl2lds16(const void* g, void* l) {
    __builtin_amdgcn_global_load_lds(
        (const __attribute__((address_space(1))) unsigned int*)g,
        (__attribute__((address_space(3))) unsigned int*)l, 16, 0, 0);
}

// ---------------- bzero: zero only X''' halo (rho=0 | cwo=0 | d in {0,17}) --
__global__ __launch_bounds__(256)
void bzero(uint4* __restrict__ xpp) {
    const uint4 z = {0u, 0u, 0u, 0u};
    const int total = 935936;
    for (int idx = blockIdx.x * 256 + threadIdx.x; idx < total;
         idx += gridDim.x * 256) {
        int u;
        if (idx < 276480) {
            int slab = idx / 2160, off = idx % 2160;
            u = slab * 32400 + off;
        } else if (idx < 534528) {
            int k = idx - 276480;
            int run = k / 144, off = k % 144;
            int slab = run / 14, rho = run % 14 + 1;
            u = slab * 32400 + rho * 2160 + off;
        } else {
            int k = idx - 534528;
            int run = k / 8, off = k % 8;
            int slab = run / 392, r2 = run % 392;
            int rho = r2 / 28 + 1, r3 = r2 % 28;
            int cwo = r3 / 2 + 1, d = (r3 & 1) * 17;
            u = slab * 32400 + rho * 2160 + cwo * 144 + d * 8 + off;
        }
        xpp[u] = z;
    }
}

// ---------------- T1: X (f32) -> X''' (bf16, space-to-depth, d-innermost) --
__global__ __launch_bounds__(512)
void xform_x(const float* __restrict__ xin, __hip_bfloat16* __restrict__ xpp) {
    extern __shared__ __hip_bfloat16 Xl[];
    const int bid = blockIdx.x;
    const int rho = bid % 14, d = (bid / 14) % 16, b = bid / 224;
    const int tid = threadIdx.x;
    for (int f = tid; f < 64 * 8 * 28; f += 512) {
        int ci = f / 224, rem = f % 224;
        int r = rem / 28, c4 = (rem % 28) * 4;
        const float4 v = *(const float4*)&xin[
            ((((size_t)b * 64 + ci) * 16 + d) * 112 + (rho * 8 + r)) * 112 + c4];
        const float vv[4] = {v.x, v.y, v.z, v.w};
#pragma unroll
        for (int u = 0; u < 4; ++u) {
            int c = c4 + u;
            Xl[(r * 112 + c) * 64 + (ci ^ ((c & 7) << 3))] = __float2bfloat16(vv[u]);
        }
    }
    __syncthreads();
    for (int f = tid; f < 896 * 8; f += 512) {
        int pos = f >> 3, j = f & 7;
        int r = pos / 112, c = pos % 112;
        int cw = c & 7, cwo = c >> 3;
        uint4 v = *(const uint4*)&Xl[pos * 64 + ((j * 8) ^ ((c & 7) << 3))];
        size_t dst = (((((size_t)(r * 8 + cw) * 2 + b) * 15 + (rho + 1)) * 15
                       + (cwo + 1)) * 18 + (d + 1)) * 64 + j * 8;
        *(uint4*)(xpp + dst) = v;
    }
}

// ---------------- T2: W (f32) -> W''[hw][tap][co64][cic8x16B] (bf16) -------
__global__ __launch_bounds__(256)
void xform_w(const float* __restrict__ wt, __hip_bfloat16* __restrict__ wpp) {
    __shared__ __hip_bfloat16 lw[8 * 27 * 72];
    const int hw = blockIdx.x >> 3, cc = blockIdx.x & 7;
    for (int f = threadIdx.x; f < 8 * 64 * 27; f += 256) {
        int k = f % 27, ci = (f / 27) % 64, co = f / (27 * 64);
        float v = wt[(size_t)hw * 110592 + (size_t)(cc * 8 + co) * 1728 + ci * 27 + k];
        lw[(co * 27 + k) * 72 + ci] = __float2bfloat16(v);
    }
    __syncthreads();
    for (int f = threadIdx.x; f < 27 * 8 * 8; f += 256) {
        int cic = f % 8, co = (f / 8) % 8, k = f / 64;
        uint4 v = *(const uint4*)&lw[(co * 27 + k) * 72 + cic * 8];
        size_t dst = (((size_t)hw * 27 + k) * 64 + (cc * 8 + co)) * 64 + cic * 8;
        *(uint4*)(wpp + dst) = v;
    }
}

// ---------------- GEMM: per (h,w,b,mc): [224m x 64co], m=(wo14,t16) --------
// 256 thr / 4 waves (mg2 x ng2), wave = 7 m-tiles x 2 n-tiles (r3-verified).
// 9 round-pairs p=(kh,kw); A staged ONCE per p as full-18d line halves
// (16128 B used, buffer padded to 16384 B — global_load_lds writes base+
// lane*16 linearly, tail lands in pad, NO per-lane dst clamp allowed);
// taps for line p are {p, p+9, p+18} (tap = kd*9 + kh*3 + kw), B staged ONCE
// per tap to ring-6 [p&1][kd] x 8 KB, one pair ahead.
// Staged/block = 290K + 216K = 506 KB (2.3x less than r3-r8's ~1.1 MB).
// LDS 81920 B = 2 blk/CU. Simple sync: stage -> compute -> __syncthreads.

__global__ __launch_bounds__(256, 2)
void patgemm(const __hip_bfloat16* __restrict__ xpp,
             const char* __restrict__ wppc,
             const float* __restrict__ bs,
             float* __restrict__ out) {
    extern __shared__ char smem[];  // A: 2 x 16384 (16128 used) | B: 6 x 8192
    const char* xppc = (const char*)xpp;
    const int bid = blockIdx.x;
    const int h = bid & 7, w = (bid >> 3) & 7, b = (bid >> 6) & 1, mc = bid >> 7;
    const int hw = h * 8 + w;
    const int tid = threadIdx.x, wv = tid >> 6;
    const int lane = tid & 63, col = lane & 15, quad = lane >> 4;
    const int mg = wv >> 1, ng = wv & 1;

    // A staging: slot u -> (wo = u/72, d = (u%72)>>2, q' = u&3); src chunk
    // q = q' ^ ((d>>1)&3). dst linear u*16 (UNclamped; src clamped only).
    uint32_t aoff[4];
#pragma unroll
    for (int i = 0; i < 4; ++i) {
        int u = tid + i * 256; if (u > 1007) u = 1007;   // src clamp only
        int wo = u / 72, rem = u - wo * 72;
        int d = rem >> 2, qp = rem & 3, q = qp ^ ((d >> 1) & 3);
        aoff[i] = (uint32_t)(wo * 2304 + d * 128 + q * 16);
    }
    // B staging: u -> co = u>>3, ch = u&7; src chunk ch^(co&7) (r3-verified)
    uint32_t boff[2];
#pragma unroll
    for (int i = 0; i < 2; ++i) {
        int u = tid + i * 256;
        boff[i] = (uint32_t)((u >> 3) * 128 + (((u & 7) ^ ((u >> 3) & 7)) << 4));
    }
    // A read: row d = col+kd (64B rows), chunk quad^((d>>1)&3) [r7: 0-conflict]
    uint32_t rofs[3];
#pragma unroll
    for (int kd = 0; kd < 3; ++kd) {
        int d = col + kd;
        rofs[kd] = (uint32_t)(d * 64 + ((quad ^ ((d >> 1) & 3)) << 4));
    }
    // B read: co-row 128B, chunk (hf*4+quad)^(co&7) (r3-verified)
    uint32_t bofsw[2];
#pragma unroll
    for (int hf = 0; hf < 2; ++hf)
        bofsw[hf] = (uint32_t)(col * 128 + (((hf * 4 + quad) ^ (col & 7)) << 4));

    f32x4 acc[7][2];
#pragma unroll
    for (int j = 0; j < 7; ++j)
#pragma unroll
        for (int n = 0; n < 2; ++n) acc[j][n] = (f32x4){0.f, 0.f, 0.f, 0.f};

    const char* wbase = wppc + (size_t)hw * 221184;

    auto lineBase = [&](int p) -> const char* {
        const int kh = (p >= 6) ? 2 : (p >= 3 ? 1 : 0);
        const int kw = p - 3 * kh;
        const int r0 = h + kh - 7, c0 = w + kw - 7;
        return xppc + (size_t)(((((r0 & 7) * 8 + (c0 & 7)) * 2 + b) * 15
                    + ((r0 >> 3) + 1 + mc)) * 15 + ((c0 >> 3) + 1)) * 2304;
    };
    auto STGA = [&](const char* lb, int hf, int buf) {
#pragma unroll
        for (int i = 0; i < 4; ++i)
            gl2lds16(lb + aoff[i] + hf * 64,
                     smem + buf * 16384 + (tid + i * 256) * 16);
    };
    auto STGB = [&](int tap, int slot) {
#pragma unroll
        for (int i = 0; i < 2; ++i)
            gl2lds16(wbase + (size_t)tap * 8192 + boff[i],
                     smem + 32768 + slot * 8192 + (tid + i * 256) * 16);
    };

    // prologue: A(p=0,hf0)->buf0; B taps {0,9,18} (kd=0,1,2) -> slots 0,1,2
    const char* lb = lineBase(0);
    STGA(lb, 0, 0);
    STGB(0, 0); STGB(9, 1); STGB(18, 2);
    __syncthreads();

#pragma unroll 1
    for (int p = 0; p < 9; ++p) {
        const int pp = p & 1;
        // ---- round (p, hf=0): reads buf0 + B slots pp*3+kd
        STGA(lb, 1, 1);                       // same line, other ci-half
        if (p < 8) {                          // taps for line p+1: {p+1+9kd}
            const int sb = (1 - pp) * 3;
            STGB(p + 1, sb); STGB(p + 10, sb + 1); STGB(p + 19, sb + 2);
        }
#pragma unroll
        for (int kd = 0; kd < 3; ++kd) {
            const char* Bb = smem + 32768 + (pp * 3 + kd) * 8192;
            short8 bf0 = *(const short8*)(Bb + (ng * 2 + 0) * 2048 + bofsw[0]);
            short8 bf1 = *(const short8*)(Bb + (ng * 2 + 1) * 2048 + bofsw[0]);
#pragma unroll
            for (int j = 0; j < 7; ++j) {
                short8 af = *(const short8*)(smem + (mg * 7 + j) * 1152 + rofs[kd]);
                acc[j][0] = __builtin_amdgcn_mfma_f32_16x16x32_bf16(af, bf0, acc[j][0], 0, 0, 0);
                acc[j][1] = __builtin_amdgcn_mfma_f32_16x16x32_bf16(af, bf1, acc[j][1], 0, 0, 0);
            }
        }
        __syncthreads();
        // ---- round (p, hf=1): reads buf1 + same B slots, other ci-half
        if (p < 8) { lb = lineBase(p + 1); STGA(lb, 0, 0); }
#pragma unroll
        for (int kd = 0; kd < 3; ++kd) {
            const char* Bb = smem + 32768 + (pp * 3 + kd) * 8192;
            short8 bf0 = *(const short8*)(Bb + (ng * 2 + 0) * 2048 + bofsw[1]);
            short8 bf1 = *(const short8*)(Bb + (ng * 2 + 1) * 2048 + bofsw[1]);
#pragma unroll
            for (int j = 0; j < 7; ++j) {
                short8 af = *(const short8*)(smem + 16384 + (mg * 7 + j) * 1152 + rofs[kd]);
                acc[j][0] = __builtin_amdgcn_mfma_f32_16x16x32_bf16(af, bf0, acc[j][0], 0, 0, 0);
                acc[j][1] = __builtin_amdgcn_mfma_f32_16x16x32_bf16(af, bf1, acc[j][1], 0, 0, 0);
            }
        }
        __syncthreads();
    }

    // epilogue (r3-verified): co = (ng*2+n)*16+col, t = quad*4+jj, wo = mg*7+j
    const float* bsl = bs + hw * 64;
    const int y = 8 * mc + h;
#pragma unroll
    for (int j = 0; j < 7; ++j) {
        const int x = 8 * (mg * 7 + j) + w;
#pragma unroll
        for (int n = 0; n < 2; ++n) {
            const int co = (ng * 2 + n) * 16 + col;
            const float bv = bsl[co];
#pragma unroll
            for (int jj = 0; jj < 4; ++jj) {
                const int t = quad * 4 + jj;
                out[((((size_t)b * 64 + co) * 16 + t) * 112 + y) * 112 + x]
                    = acc[j][n][jj] + bv;
            }
        }
    }
}

// ---------------- fallback: round-1 fp32 kernel (used if ws too small) -----
#define XL_ROWSTRIDE 116
#define WL_WSTRIDE (17*27)

__global__ __launch_bounds__(256, 3)
void patconv3d_fp32(const float* __restrict__ xin,
                    const float* __restrict__ wt,
                    const float* __restrict__ bs,
                    float* __restrict__ out) {
    __shared__ float Xl[3*3*7*XL_ROWSTRIDE];
    __shared__ float Wl[8*WL_WSTRIDE];
    const int bid = blockIdx.x;
    const int ct = bid & 3, hb = (bid >> 2) & 1, h = (bid >> 3) & 7;
    const int t = (bid >> 6) & 15, b = (bid >> 10) & 1;
    const int tid = threadIdx.x;
    const int xl = tid & 127, cg = tid >> 7;
    const int xr = (xl < 112) ? xl : 111;
    const int wq = xl & 7;
    float acc[8][7];
#pragma unroll
    for (int c = 0; c < 8; ++c)
#pragma unroll
        for (int ho = 0; ho < 7; ++ho) acc[c][ho] = 0.f;
    for (int ci = 0; ci < 64; ++ci) {
        __syncthreads();
        for (int idx = tid; idx < 3 * 3 * 7 * 114; idx += 256) {
            int c = idx % 114, rest = idx / 114;
            int ho = rest % 7; rest /= 7;
            int kh = rest % 3, kd = rest / 3;
            int r = 8 * (hb * 7 + ho) + h + kh - 7;
            int d = t + kd - 1, colx = c - 7;
            float v = 0.f;
            if (r >= 0 && d >= 0 && d < 16 && colx >= 0)
                v = xin[(((size_t)(b * 64 + ci) * 16 + d) * 112 + r) * 112 + colx];
            Xl[((kd * 3 + kh) * 7 + ho) * XL_ROWSTRIDE + c] = v;
        }
        for (int idx = tid; idx < 8 * 16 * 27; idx += 256) {
            int k2 = idx % 27, rest = idx / 27;
            int co_l = rest % 16, wi = rest / 16;
            Wl[wi * WL_WSTRIDE + co_l * 27 + k2] =
                wt[(((size_t)(h * 8 + wi) * 64 + (ct * 16 + co_l)) * 64 + ci) * 27 + k2];
        }
        __syncthreads();
#pragma unroll
        for (int kd = 0; kd < 3; ++kd)
#pragma unroll
            for (int kh = 0; kh < 3; ++kh)
#pragma unroll
                for (int kw = 0; kw < 3; ++kw) {
                    const int k2 = (kd * 3 + kh) * 3 + kw;
                    float xv[7];
#pragma unroll
                    for (int ho = 0; ho < 7; ++ho)
                        xv[ho] = Xl[((kd * 3 + kh) * 7 + ho) * XL_ROWSTRIDE + xr + kw];
                    float wv[8];
#pragma unroll
                    for (int c = 0; c < 8; ++c)
                        wv[c] = Wl[wq * WL_WSTRIDE + (cg * 8 + c) * 27 + k2];
#pragma unroll
                    for (int c = 0; c < 8; ++c)
#pragma unroll
                        for (int ho = 0; ho < 7; ++ho)
                            acc[c][ho] += wv[c] * xv[ho];
                }
    }
    if (xl < 112) {
#pragma unroll
        for (int c = 0; c < 8; ++c) {
            const int co = ct * 16 + cg * 8 + c;
            const float bv = bs[(h * 8 + wq) * 64 + co];
#pragma unroll
            for (int ho = 0; ho < 7; ++ho) {
                const int y = 8 * (hb * 7 + ho) + h;
                out[(((size_t)(b * 64 + co) * 16 + t) * 112 + y) * 112 + xl] = acc[c][ho] + bv;
            }
        }
    }
}

extern "C" void kernel_launch(void* const* d_in, const int* in_sizes, int n_in,
                              void* d_out, int out_size, void* d_ws, size_t ws_size,
                              hipStream_t stream) {
    const float* x  = (const float*)d_in[0];
    const float* wg = (const float*)d_in[1];
    const float* bi = (const float*)d_in[2];
    float* out = (float*)d_out;
    if (ws_size >= WPP_BYTES + XPP_BYTES) {
        __hip_bfloat16* wpp = (__hip_bfloat16*)d_ws;
        __hip_bfloat16* xpp = (__hip_bfloat16*)((char*)d_ws + WPP_BYTES);
        bzero<<<1024, 256, 0, stream>>>((uint4*)xpp);
        xform_x<<<448, 512, 114688, stream>>>(x, xpp);
        xform_w<<<512, 256, 0, stream>>>(wg, wpp);
        patgemm<<<1792, 256, 81920, stream>>>(xpp, (const char*)wpp, bi, out);
    } else {
        patconv3d_fp32<<<2048, 256, 0, stream>>>(x, wg, bi, out);
    }
}